// Round 2
// baseline (163.036 us; speedup 1.0000x reference)
//
#include <hip/hip_runtime.h>
#include <hip/hip_bf16.h>

// Problem constants (from reference)
#define NW   8192
#define NS   8192
#define FD   1024
#define EMB  128
#define QN   1024
#define NC   80

typedef unsigned short ushort_t;
typedef unsigned int   uint_t;
typedef __attribute__((ext_vector_type(8))) short short8;
typedef __attribute__((ext_vector_type(4))) float f32x4;

// ---------- workspace layout (element offsets, 4B units) ----------
#define OFF_Q      0u           // float [NW*EMB]
#define OFF_K      1048576u     // float [NS*EMB]
#define OFF_WTQ    2097152u     // ushort[1024*128]  tiled [kb(16)][kg(8)][n(128)][8]
#define OFF_WTK    2129920u     // ushort[1024*128]
#define OFF_HIST   2752512u     // int   [128]
#define OFF_RANK   2752640u     // int   [NW]
#define OFF_CNT    2760832u     // int   [1] completion counter
#define OFF_BHS    2785408u     // int   [32*NC]
#define OFF_BHW    2787968u     // int   [32*NC]
#define OFF_ACC    2790528u     // float [2] : {sum_ce, valid_count}
#define OFF_QT     2790532u     // ushort[1024*128]  swizzled slots: n*16 + (c ^ (n&15))
#define OFF_TABLE  3000000u     // int   [NC*8192]

__device__ __forceinline__ ushort_t f2bf(float f) {   // fp32 -> bf16 RNE
    uint_t u = __float_as_uint(f);
    u = (u + 0x7fffu + ((u >> 16) & 1u)) >> 16;
    return (ushort_t)u;
}
__device__ __forceinline__ uint_t pack2(float a, float b) {
    return (uint_t)f2bf(a) | ((uint_t)f2bf(b) << 16);
}

// async global->LDS, 16B per lane; LDS dest = WAVE-UNIFORM base + lane*16
#define GLOAD_LDS16(gp, lp)                                                     \
    __builtin_amdgcn_global_load_lds(                                           \
        (const __attribute__((address_space(1))) void*)(gp),                    \
        (__attribute__((address_space(3))) void*)(lp), 16, 0, 0)

// ============ K1: fused convert/transpose + per-block label histograms + init ============
// z<2: W[1024][128] -> Wt tiled [kb(16)][kg(8)][n(128)][8]  (k = kb*64 + kg*8 + j)
// z=2: queue[128][1024] -> Qt swizzled: 16B slot (n*16 + ((k>>3) ^ (n&15)))
__global__ __launch_bounds__(256) void cvtbh_k(const float* __restrict__ Wq,
                                               const float* __restrict__ Wk,
                                               const float* __restrict__ queue,
                                               const int* __restrict__ s_lab,
                                               const int* __restrict__ w_lab,
                                               ushort_t* __restrict__ Wtq,
                                               ushort_t* __restrict__ Wtk,
                                               ushort_t* __restrict__ Qt,
                                               int* __restrict__ bhs,
                                               int* __restrict__ bhw,
                                               float* __restrict__ accum,
                                               int* __restrict__ counter) {
    int bx = blockIdx.x;
    int t = threadIdx.x;
    if (bx >= 384) {   // ---- bh part ----
        __shared__ int h[NC];
        int b2 = bx - 384, z = b2 >> 5, cb = b2 & 31;
        const int* lab = z ? w_lab : s_lab;
        int* bh = z ? bhw : bhs;
        if (t < NC) h[t] = 0;
        __syncthreads();
        atomicAdd(&h[lab[cb * 256 + t]], 1);
        __syncthreads();
        if (t < NC) bh[cb * NC + t] = h[t];
        return;
    }
    // ---- cvt part ----
    __shared__ float tile[32][33];
    int z = bx >> 7, flat = bx & 127;
    if (z == 0 && flat == 0) {
        if (t < 2) accum[t] = 0.0f;
        if (t == 2) *counter = 0;
    }
    const float* in; ushort_t* out; int r0, c0, C;
    if (z < 2) { in = z ? Wk : Wq; out = z ? Wtk : Wtq; C = 128;
                 r0 = (flat >> 2) * 32; c0 = (flat & 3) * 32; }
    else       { in = queue; out = Qt; C = 1024;
                 r0 = (flat & 3) * 32; c0 = (flat >> 2) * 32; }
    int i = t >> 3, j0 = (t & 7) * 4;
    float4 v = *(const float4*)(in + (size_t)(r0 + i) * C + c0 + j0);
    tile[i][j0] = v.x; tile[i][j0 + 1] = v.y; tile[i][j0 + 2] = v.z; tile[i][j0 + 3] = v.w;
    __syncthreads();
    uint2 pk;
    pk.x = pack2(tile[j0][i], tile[j0 + 1][i]);
    pk.y = pack2(tile[j0 + 2][i], tile[j0 + 3][i]);
    size_t oaddr;
    int k0 = r0 + j0, n = c0 + i;
    if (z < 2) {
        oaddr = (size_t)(k0 >> 6) * 8192 + (size_t)((k0 >> 3) & 7) * 1024
              + (size_t)n * 8 + (k0 & 7);
    } else {
        int c = k0 >> 3;
        oaddr = ((size_t)n * 16 + (c ^ (n & 15))) * 8 + (k0 & 7);
    }
    *(uint2*)(out + oaddr) = pk;
}

// ============ K2: encoder GEMM (32x128 tile, BK=64) + fused ranktab ============
// blocks [0,64): ranktab — rank/table/hist from cvtbh block-histograms (FIRST so
//   they don't tail-queue behind GEMM blocks at 2 blocks/CU occupancy).
// blocks [64,576): GEMM — (bx-64)>>8 = encoder, (bx-64)&255 = 32-row tile; 4 waves 2x2.
//   T3/T4 counted-vmcnt pipeline: 3 LDS buffers x 24KB (A 8KB swizzled on global
//   gather, B 16KB linear from tiled Wt). Per iter kb: s_waitcnt vmcnt(6) (chunk kb
//   done, chunk kb+1's 6 loads stay IN FLIGHT across the barrier), raw s_barrier,
//   stage chunk kb+2 into buf[(kb+2)%3], then 12 ds_read_b128 + 8 MFMA per wave.
//   Buffer distance 3 => buffer overwritten by chunk kb+2 was last read iter kb-1,
//   completed by all waves before this barrier. Tail iter peeled with vmcnt(0).
__global__ __launch_bounds__(256) void enc_mfma_k(const float* __restrict__ A0,
                                                  const float* __restrict__ A1,
                                                  const ushort_t* __restrict__ Wt0,
                                                  const ushort_t* __restrict__ Wt1,
                                                  const float* __restrict__ b0_,
                                                  const float* __restrict__ b1_,
                                                  float* __restrict__ out0,
                                                  float* __restrict__ out1,
                                                  const int* __restrict__ s_lab,
                                                  const int* __restrict__ w_lab,
                                                  const int* __restrict__ bhs,
                                                  const int* __restrict__ bhw,
                                                  int* __restrict__ table,
                                                  int* __restrict__ rank,
                                                  int* __restrict__ hist) {
    __shared__ __align__(16) char smem[73728];   // 3 x (8KB A + 16KB B)

    int bx = blockIdx.x;
    int t = threadIdx.x;

    if (bx < 64) {   // ---- fused ranktab part ----
        int* ll = (int*)smem;
        int b2 = bx, z = b2 >> 5, cb = b2 & 31;
        const int* lab = z ? w_lab : s_lab;
        const int* bh = z ? bhw : bhs;
        int j = cb * 256 + t;
        int c = lab[j];
        ll[t] = c;
        __syncthreads();
        int r = 0;
        for (int b = 0; b < cb; b++) r += bh[b * NC + c];
        for (int jj = 0; jj < t; jj++) r += (ll[jj] == c) ? 1 : 0;
        if (z) rank[j] = r;
        else   table[c * 8192 + r] = j;
        if (b2 == 0 && t < 128) {
            int h = 0;
            if (t < NC)
                for (int b = 0; b < 32; b++) h += bhs[b * NC + t];
            hist[t] = h;
        }
        return;
    }

    // ---- GEMM part ----
    int bxg = bx - 64;
    int which = bxg >> 8;
    int mtile = bxg & 255;
    const float*    A    = which ? A1 : A0;
    const ushort_t* Wt   = which ? Wt1 : Wt0;
    const float*    bias = which ? b1_ : b0_;
    float*          out  = which ? out1 : out0;
    int row0 = mtile * 32;

    int wv = t >> 6, ln = t & 63;
    int wm = wv >> 1, wn = wv & 1;
    int lane15 = ln & 15, kg = ln >> 4;

    // A staging: wave wv, instr i in {0,1}: slot = wv*128 + i*64 + ln -> row r = slot>>4,
    // slot_c = ln&15, global chunk c_g = (ln&15) ^ (r&15)
    int ar0 = wv * 8 + (ln >> 4);
    int ar1 = ar0 + 4;
    const float* gA0 = A + (size_t)(row0 + ar0) * FD + (((ln & 15) ^ (ar0 & 15))) * 4;
    const float* gA1 = A + (size_t)(row0 + ar1) * FD + (((ln & 15) ^ (ar1 & 15))) * 4;
    // B staging: wave wv covers slots wv*256 + i*64 + ln (i 0..3), linear in tiled Wt
    const ushort_t* gB = Wt + (size_t)wv * 2048 + ln * 8;

    f32x4 acc[4];
#pragma unroll
    for (int nt = 0; nt < 4; nt++) acc[nt] = (f32x4){0.f, 0.f, 0.f, 0.f};

#define STAGE(BUF, KB)                                                           \
    { char* sb = smem + (BUF) * 24576;                                           \
      GLOAD_LDS16(gA0 + (size_t)(KB) * 64, sb + wv * 2048);                      \
      GLOAD_LDS16(gA1 + (size_t)(KB) * 64, sb + wv * 2048 + 1024);               \
      const ushort_t* gb = gB + (size_t)(KB) * 8192;                             \
      char* bb = sb + 8192 + wv * 4096;                                          \
      GLOAD_LDS16(gb,        bb);                                                \
      GLOAD_LDS16(gb + 512,  bb + 1024);                                         \
      GLOAD_LDS16(gb + 1024, bb + 2048);                                         \
      GLOAD_LDS16(gb + 1536, bb + 3072); }

#define K2_ITER(KB, CURB, STB, VMSTR)                                            \
    { asm volatile("s_waitcnt vmcnt(" VMSTR ")" ::: "memory");                   \
      __builtin_amdgcn_s_barrier();                                              \
      __builtin_amdgcn_sched_barrier(0);                                         \
      if ((KB) < 14) STAGE(STB, (KB) + 2)                                        \
      { char* lb = smem + (CURB) * 24576;                                        \
        _Pragma("unroll")                                                        \
        for (int ks = 0; ks < 2; ks++) {                                         \
            int r_l = wm * 16 + lane15;                                          \
            int c0 = ks * 8 + kg * 2;                                            \
            float4 alo = *(const float4*)(lb + ((size_t)r_l * 16 + ((c0)     ^ (r_l & 15))) * 16); \
            float4 ahi = *(const float4*)(lb + ((size_t)r_l * 16 + ((c0 + 1) ^ (r_l & 15))) * 16); \
            uint4 pk;                                                            \
            pk.x = pack2(alo.x, alo.y); pk.y = pack2(alo.z, alo.w);              \
            pk.z = pack2(ahi.x, ahi.y); pk.w = pack2(ahi.z, ahi.w);              \
            short8 af = __builtin_bit_cast(short8, pk);                          \
            int kgg = ks * 4 + kg;                                               \
            _Pragma("unroll")                                                    \
            for (int nt = 0; nt < 4; nt++) {                                     \
                uint4 bv = *(const uint4*)(lb + 8192 +                           \
                            ((size_t)kgg * 128 + wn * 64 + nt * 16 + lane15) * 16); \
                acc[nt] = __builtin_amdgcn_mfma_f32_16x16x32_bf16(               \
                    af, __builtin_bit_cast(short8, bv), acc[nt], 0, 0, 0);       \
            }                                                                    \
        } }                                                                      \
    }

    STAGE(0, 0)
    STAGE(1, 1)
#pragma unroll 1
    for (int kb3 = 0; kb3 < 15; kb3 += 3) {
        K2_ITER(kb3 + 0, 0, 2, "6")
        K2_ITER(kb3 + 1, 1, 0, "6")
        K2_ITER(kb3 + 2, 2, 1, "6")
    }
    K2_ITER(15, 0, 0, "0")
#undef K2_ITER
#undef STAGE

    // epilogue: C[row][col], row = row0 + wm*16 + kg*4+j, col = wn*64 + nt*16 + lane15
#pragma unroll
    for (int nt = 0; nt < 4; nt++) {
        int col = wn * 64 + nt * 16 + lane15;
        float bv = bias[col];
        int rbase = row0 + wm * 16 + kg * 4;
#pragma unroll
        for (int j = 0; j < 4; j++)
            out[(size_t)(rbase + j) * EMB + col] = acc[nt][j] + bv;
    }
}

// ============ K3: idx + lpos + l_neg (MFMA, B direct from L2) + CE ============
// grid 512 x 256: 16 q-rows/block; Qt (256 KB) is L2-resident, so B-fragments are
// read STRAIGHT from global into registers — no LDS staging, no barriers, no
// vmcnt rendezvous. Round-1 counters showed the LDS-staged version 90% stalled
// (MfmaUtil 1.6%, VALUBusy 4.7%, HBM 1.5%, occupancy 12%): 16 barrier-coupled
// chunks of ~100cy compute each. Barrier-free waves self-hide L2 latency via ILP
// (64 independent dwordx4 loads feeding 16 independent acc chains).
// B address: granule (n*16 + (c ^ (n&15))) of swizzled Qt — byte-identical data
// to what the LDS path delivered, so K1 is untouched.
__global__ __launch_bounds__(256) void ce_mfma_k(const float* __restrict__ q,
                                                 const float* __restrict__ k,
                                                 const ushort_t* __restrict__ Qt,
                                                 const int* __restrict__ rank,
                                                 const int* __restrict__ table,
                                                 const int* __restrict__ w,
                                                 const int* __restrict__ hist,
                                                 float* __restrict__ accum,
                                                 int* __restrict__ counter,
                                                 float* __restrict__ outp) {
    __shared__ int   idx_lds[16];
    __shared__ float lpos_lds[16];
    __shared__ float mg[4][16][2];
    int t = threadIdx.x;
    int r0 = blockIdx.x * 16;

    // inline idx: idx[i] = table[w[i]][rank[i] % cnt]
    if (t < 16) {
        int i = r0 + t;
        int c = w[i];
        int cc = hist[c];
        idx_lds[t] = (cc > 0) ? table[c * 8192 + (rank[i] % cc)] : 0;
    }
    __syncthreads();

    // fused l_pos (fp32 exact): row r0+(t>>4), 16 threads x 8 floats
    {
        int rr = t >> 4;
        int o = (t & 15) * 8;
        const float4* qa = (const float4*)(q + (size_t)(r0 + rr) * EMB + o);
        const float4* ka = (const float4*)(k + (size_t)idx_lds[rr] * EMB + o);
        float4 a0 = qa[0], b0 = ka[0], a1 = qa[1], b1 = ka[1];
        float s = a0.x * b0.x + a0.y * b0.y + a0.z * b0.z + a0.w * b0.w
                + a1.x * b1.x + a1.y * b1.y + a1.z * b1.z + a1.w * b1.w;
        s += __shfl_xor(s, 1); s += __shfl_xor(s, 2);
        s += __shfl_xor(s, 4); s += __shfl_xor(s, 8);
        if ((t & 15) == 0) lpos_lds[rr] = s;
    }

    int wv = t >> 6, ln = t & 63;
    int lane15 = ln & 15, kg = ln >> 4;

    // A-frags direct from q global (all waves same 16 rows)
    short8 afr[4];
#pragma unroll
    for (int ks = 0; ks < 4; ks++) {
        const float4* p = (const float4*)(q + (size_t)(r0 + lane15) * EMB + ks * 32 + kg * 8);
        float4 a = p[0], b = p[1];
        uint4 pk;
        pk.x = pack2(a.x, a.y); pk.y = pack2(a.z, a.w);
        pk.z = pack2(b.x, b.y); pk.w = pack2(b.z, b.w);
        afr[ks] = __builtin_bit_cast(short8, pk);
    }

    f32x4 acc[16];
#pragma unroll
    for (int nc = 0; nc < 16; nc++) acc[nc] = (f32x4){0.f, 0.f, 0.f, 0.f};

    // l_neg: 16 chunks x 4 k-slices, B straight from L2-resident Qt.
    // col n_g = nc*64 + wv*16 + lane15; k-granule c = ks*4 + kg; n_g&15 == lane15.
#pragma unroll
    for (int nc = 0; nc < 16; nc++) {
        int n_g = nc * 64 + wv * 16 + lane15;
        const ushort_t* bp = Qt + (size_t)n_g * 128;
#pragma unroll
        for (int ks = 0; ks < 4; ks++) {
            int c = ks * 4 + kg;
            uint4 bb = *(const uint4*)(bp + (size_t)(c ^ lane15) * 8);
            acc[nc] = __builtin_amdgcn_mfma_f32_16x16x32_bf16(
                afr[ks], __builtin_bit_cast(short8, bb), acc[nc], 0, 0, 0);
        }
    }

    // deferred softmax: one max/exp/sum pass over the 64 register logits
#pragma unroll
    for (int j = 0; j < 4; j++) {
        float mx = -1e30f;
#pragma unroll
        for (int nc = 0; nc < 16; nc++) mx = fmaxf(mx, acc[nc][j]);
        mx = fmaxf(mx, __shfl_xor(mx, 1));
        mx = fmaxf(mx, __shfl_xor(mx, 2));
        mx = fmaxf(mx, __shfl_xor(mx, 4));
        mx = fmaxf(mx, __shfl_xor(mx, 8));
        float s = 0.f;
#pragma unroll
        for (int nc = 0; nc < 16; nc++) s += __expf(acc[nc][j] - mx);
        s += __shfl_xor(s, 1);
        s += __shfl_xor(s, 2);
        s += __shfl_xor(s, 4);
        s += __shfl_xor(s, 8);
        if (lane15 == 0) {
            mg[wv][kg * 4 + j][0] = mx;
            mg[wv][kg * 4 + j][1] = s;
        }
    }
    __syncthreads();
    if (wv == 0) {
        float cv = 0.f, cc = 0.f;
        if (t < 16) {
            int i = r0 + t;
            float m0 = mg[0][t][0], l0 = mg[0][t][1];
            float m1 = mg[1][t][0], l1 = mg[1][t][1];
            float m2 = mg[2][t][0], l2 = mg[2][t][1];
            float m3 = mg[3][t][0], l3 = mg[3][t][1];
            float lp = lpos_lds[t];
            float m = fmaxf(fmaxf(fmaxf(m0, m1), fmaxf(m2, m3)), lp);
            float l = l0 * __expf(m0 - m) + l1 * __expf(m1 - m)
                    + l2 * __expf(m2 - m) + l3 * __expf(m3 - m) + __expf(lp - m);
            float ce = -(lp - m - __logf(l));
            if (hist[w[i]] > 0) { cv = ce; cc = 1.f; }
        }
        cv += __shfl_xor(cv, 1);  cc += __shfl_xor(cc, 1);
        cv += __shfl_xor(cv, 2);  cc += __shfl_xor(cc, 2);
        cv += __shfl_xor(cv, 4);  cc += __shfl_xor(cc, 4);
        cv += __shfl_xor(cv, 8);  cc += __shfl_xor(cc, 8);
        if (t == 0) {
            atomicAdd(&accum[0], cv);
            atomicAdd(&accum[1], cc);
            __threadfence();
            int done = atomicAdd(counter, 1);
            if (done == 511) {   // last block finalizes
                float s = atomicAdd(&accum[0], 0.0f);
                float c = atomicAdd(&accum[1], 0.0f);
                outp[0] = s / fmaxf(c, 1.0f);
            }
        }
    }
}

extern "C" void kernel_launch(void* const* d_in, const int* in_sizes, int n_in,
                              void* d_out, int out_size, void* d_ws, size_t ws_size,
                              hipStream_t stream) {
    const float* feats_strong = (const float*)d_in[0];
    const float* feats_weak   = (const float*)d_in[1];
    const int*   s_lab        = (const int*)d_in[2];
    const int*   w_lab        = (const int*)d_in[3];
    const float* Wq           = (const float*)d_in[4];
    const float* bq           = (const float*)d_in[5];
    const float* Wk           = (const float*)d_in[6];
    const float* bk           = (const float*)d_in[7];
    const float* queue        = (const float*)d_in[8];

    float*    wsf = (float*)d_ws;
    int*      wsi = (int*)d_ws;

    float*    q_g   = wsf + OFF_Q;
    float*    k_g   = wsf + OFF_K;
    int*      table = wsi + OFF_TABLE;
    ushort_t* Wtq   = (ushort_t*)(wsi + OFF_WTQ);
    ushort_t* Wtk   = (ushort_t*)(wsi + OFF_WTK);
    int*      hist  = wsi + OFF_HIST;
    int*      rank  = wsi + OFF_RANK;
    int*      cnt   = wsi + OFF_CNT;
    int*      bhs   = wsi + OFF_BHS;
    int*      bhw   = wsi + OFF_BHW;
    float*    accum = wsf + OFF_ACC;
    ushort_t* Qt    = (ushort_t*)(wsi + OFF_QT);

    // K1: bf16 convert/transpose (BK=64 W-tiling, swizzled Qt) + histograms + init
    cvtbh_k<<<448, 256, 0, stream>>>(Wq, Wk, queue, s_lab, w_lab,
                                     Wtq, Wtk, Qt, bhs, bhw, accum, cnt);
    // K2: both encoder GEMMs (32x128 tiles, 3-buf counted-vmcnt pipeline) + ranktab
    enc_mfma_k<<<576, 256, 0, stream>>>(feats_weak, feats_strong, Wtq, Wtk, bq, bk, q_g, k_g,
                                        s_lab, w_lab, bhs, bhw, table, rank, hist);
    // K3: idx + lpos + l_neg GEMM (B direct from L2, barrier-free) + CE + finalize
    ce_mfma_k<<<512, 256, 0, stream>>>(q_g, k_g, Qt, rank, table, w_lab, hist,
                                       accum, cnt, (float*)d_out);
}

// Round 3
// 142.408 us; speedup vs baseline: 1.1448x; 1.1448x over previous
//
#include <hip/hip_runtime.h>
#include <hip/hip_bf16.h>

// Problem constants (from reference)
#define NW   8192
#define NS   8192
#define FD   1024
#define EMB  128
#define QN   1024
#define NC   80

typedef unsigned short ushort_t;
typedef unsigned int   uint_t;
typedef __attribute__((ext_vector_type(8))) short short8;
typedef __attribute__((ext_vector_type(4))) float f32x4;

// ---------- workspace layout (element offsets, 4B units) ----------
#define OFF_Q      0u           // float [NW*EMB]
#define OFF_K      1048576u     // float [NS*EMB]
#define OFF_WTQ    2097152u     // ushort[1024*128]  tiled [kb(16)][kg(8)][n(128)][8]
#define OFF_WTK    2129920u     // ushort[1024*128]
#define OFF_HIST   2752512u     // int   [128]
#define OFF_RANK   2752640u     // int   [NW]
#define OFF_CNT    2760832u     // int   [1] completion counter (unused now)
#define OFF_PART   2760960u     // float [1024] : per-block {sum_ce, valid} partials
#define OFF_BHS    2785408u     // int   [32*NC]
#define OFF_BHW    2787968u     // int   [32*NC]
#define OFF_ACC    2790528u     // float [2] (unused now)
#define OFF_QT     2790532u     // ushort[1024*128]  swizzled slots: n*16 + (c ^ (n&15))
#define OFF_TABLE  3000000u     // int   [NC*8192]

__device__ __forceinline__ ushort_t f2bf(float f) {   // fp32 -> bf16 RNE
    uint_t u = __float_as_uint(f);
    u = (u + 0x7fffu + ((u >> 16) & 1u)) >> 16;
    return (ushort_t)u;
}
__device__ __forceinline__ uint_t pack2(float a, float b) {
    return (uint_t)f2bf(a) | ((uint_t)f2bf(b) << 16);
}

// async global->LDS, 16B per lane; LDS dest = WAVE-UNIFORM base + lane*16
#define GLOAD_LDS16(gp, lp)                                                     \
    __builtin_amdgcn_global_load_lds(                                           \
        (const __attribute__((address_space(1))) void*)(gp),                    \
        (__attribute__((address_space(3))) void*)(lp), 16, 0, 0)

// ============ K1: fused convert/transpose + per-block label histograms + init ============
__global__ __launch_bounds__(256) void cvtbh_k(const float* __restrict__ Wq,
                                               const float* __restrict__ Wk,
                                               const float* __restrict__ queue,
                                               const int* __restrict__ s_lab,
                                               const int* __restrict__ w_lab,
                                               ushort_t* __restrict__ Wtq,
                                               ushort_t* __restrict__ Wtk,
                                               ushort_t* __restrict__ Qt,
                                               int* __restrict__ bhs,
                                               int* __restrict__ bhw,
                                               float* __restrict__ accum,
                                               int* __restrict__ counter) {
    int bx = blockIdx.x;
    int t = threadIdx.x;
    if (bx >= 384) {   // ---- bh part ----
        __shared__ int h[NC];
        int b2 = bx - 384, z = b2 >> 5, cb = b2 & 31;
        const int* lab = z ? w_lab : s_lab;
        int* bh = z ? bhw : bhs;
        if (t < NC) h[t] = 0;
        __syncthreads();
        atomicAdd(&h[lab[cb * 256 + t]], 1);
        __syncthreads();
        if (t < NC) bh[cb * NC + t] = h[t];
        return;
    }
    // ---- cvt part ----
    __shared__ float tile[32][33];
    int z = bx >> 7, flat = bx & 127;
    if (z == 0 && flat == 0) {
        if (t < 2) accum[t] = 0.0f;
        if (t == 2) *counter = 0;
    }
    const float* in; ushort_t* out; int r0, c0, C;
    if (z < 2) { in = z ? Wk : Wq; out = z ? Wtk : Wtq; C = 128;
                 r0 = (flat >> 2) * 32; c0 = (flat & 3) * 32; }
    else       { in = queue; out = Qt; C = 1024;
                 r0 = (flat & 3) * 32; c0 = (flat >> 2) * 32; }
    int i = t >> 3, j0 = (t & 7) * 4;
    float4 v = *(const float4*)(in + (size_t)(r0 + i) * C + c0 + j0);
    tile[i][j0] = v.x; tile[i][j0 + 1] = v.y; tile[i][j0 + 2] = v.z; tile[i][j0 + 3] = v.w;
    __syncthreads();
    uint2 pk;
    pk.x = pack2(tile[j0][i], tile[j0 + 1][i]);
    pk.y = pack2(tile[j0 + 2][i], tile[j0 + 3][i]);
    size_t oaddr;
    int k0 = r0 + j0, n = c0 + i;
    if (z < 2) {
        oaddr = (size_t)(k0 >> 6) * 8192 + (size_t)((k0 >> 3) & 7) * 1024
              + (size_t)n * 8 + (k0 & 7);
    } else {
        int c = k0 >> 3;
        oaddr = ((size_t)n * 16 + (c ^ (n & 15))) * 8 + (k0 & 7);
    }
    *(uint2*)(out + oaddr) = pk;
}

// ============ K2: encoder GEMM (32x128 tile, BK=64) + fused ranktab ============
// (unchanged from round 1: 3-buf counted-vmcnt pipeline; verified passing twice)
__global__ __launch_bounds__(256) void enc_mfma_k(const float* __restrict__ A0,
                                                  const float* __restrict__ A1,
                                                  const ushort_t* __restrict__ Wt0,
                                                  const ushort_t* __restrict__ Wt1,
                                                  const float* __restrict__ b0_,
                                                  const float* __restrict__ b1_,
                                                  float* __restrict__ out0,
                                                  float* __restrict__ out1,
                                                  const int* __restrict__ s_lab,
                                                  const int* __restrict__ w_lab,
                                                  const int* __restrict__ bhs,
                                                  const int* __restrict__ bhw,
                                                  int* __restrict__ table,
                                                  int* __restrict__ rank,
                                                  int* __restrict__ hist) {
    __shared__ __align__(16) char smem[73728];   // 3 x (8KB A + 16KB B)

    int bx = blockIdx.x;
    int t = threadIdx.x;

    if (bx < 64) {   // ---- fused ranktab part ----
        int* ll = (int*)smem;
        int b2 = bx, z = b2 >> 5, cb = b2 & 31;
        const int* lab = z ? w_lab : s_lab;
        const int* bh = z ? bhw : bhs;
        int j = cb * 256 + t;
        int c = lab[j];
        ll[t] = c;
        __syncthreads();
        int r = 0;
        for (int b = 0; b < cb; b++) r += bh[b * NC + c];
        for (int jj = 0; jj < t; jj++) r += (ll[jj] == c) ? 1 : 0;
        if (z) rank[j] = r;
        else   table[c * 8192 + r] = j;
        if (b2 == 0 && t < 128) {
            int h = 0;
            if (t < NC)
                for (int b = 0; b < 32; b++) h += bhs[b * NC + t];
            hist[t] = h;
        }
        return;
    }

    // ---- GEMM part ----
    int bxg = bx - 64;
    int which = bxg >> 8;
    int mtile = bxg & 255;
    const float*    A    = which ? A1 : A0;
    const ushort_t* Wt   = which ? Wt1 : Wt0;
    const float*    bias = which ? b1_ : b0_;
    float*          out  = which ? out1 : out0;
    int row0 = mtile * 32;

    int wv = t >> 6, ln = t & 63;
    int wm = wv >> 1, wn = wv & 1;
    int lane15 = ln & 15, kg = ln >> 4;

    int ar0 = wv * 8 + (ln >> 4);
    int ar1 = ar0 + 4;
    const float* gA0 = A + (size_t)(row0 + ar0) * FD + (((ln & 15) ^ (ar0 & 15))) * 4;
    const float* gA1 = A + (size_t)(row0 + ar1) * FD + (((ln & 15) ^ (ar1 & 15))) * 4;
    const ushort_t* gB = Wt + (size_t)wv * 2048 + ln * 8;

    f32x4 acc[4];
#pragma unroll
    for (int nt = 0; nt < 4; nt++) acc[nt] = (f32x4){0.f, 0.f, 0.f, 0.f};

#define STAGE(BUF, KB)                                                           \
    { char* sb = smem + (BUF) * 24576;                                           \
      GLOAD_LDS16(gA0 + (size_t)(KB) * 64, sb + wv * 2048);                      \
      GLOAD_LDS16(gA1 + (size_t)(KB) * 64, sb + wv * 2048 + 1024);               \
      const ushort_t* gb = gB + (size_t)(KB) * 8192;                             \
      char* bb = sb + 8192 + wv * 4096;                                          \
      GLOAD_LDS16(gb,        bb);                                                \
      GLOAD_LDS16(gb + 512,  bb + 1024);                                         \
      GLOAD_LDS16(gb + 1024, bb + 2048);                                         \
      GLOAD_LDS16(gb + 1536, bb + 3072); }

#define K2_ITER(KB, CURB, STB, VMSTR)                                            \
    { asm volatile("s_waitcnt vmcnt(" VMSTR ")" ::: "memory");                   \
      __builtin_amdgcn_s_barrier();                                              \
      __builtin_amdgcn_sched_barrier(0);                                         \
      if ((KB) < 14) STAGE(STB, (KB) + 2)                                        \
      { char* lb = smem + (CURB) * 24576;                                        \
        _Pragma("unroll")                                                        \
        for (int ks = 0; ks < 2; ks++) {                                         \
            int r_l = wm * 16 + lane15;                                          \
            int c0 = ks * 8 + kg * 2;                                            \
            float4 alo = *(const float4*)(lb + ((size_t)r_l * 16 + ((c0)     ^ (r_l & 15))) * 16); \
            float4 ahi = *(const float4*)(lb + ((size_t)r_l * 16 + ((c0 + 1) ^ (r_l & 15))) * 16); \
            uint4 pk;                                                            \
            pk.x = pack2(alo.x, alo.y); pk.y = pack2(alo.z, alo.w);              \
            pk.z = pack2(ahi.x, ahi.y); pk.w = pack2(ahi.z, ahi.w);              \
            short8 af = __builtin_bit_cast(short8, pk);                          \
            int kgg = ks * 4 + kg;                                               \
            _Pragma("unroll")                                                    \
            for (int nt = 0; nt < 4; nt++) {                                     \
                uint4 bv = *(const uint4*)(lb + 8192 +                           \
                            ((size_t)kgg * 128 + wn * 64 + nt * 16 + lane15) * 16); \
                acc[nt] = __builtin_amdgcn_mfma_f32_16x16x32_bf16(               \
                    af, __builtin_bit_cast(short8, bv), acc[nt], 0, 0, 0);       \
            }                                                                    \
        } }                                                                      \
    }

    STAGE(0, 0)
    STAGE(1, 1)
#pragma unroll 1
    for (int kb3 = 0; kb3 < 15; kb3 += 3) {
        K2_ITER(kb3 + 0, 0, 2, "6")
        K2_ITER(kb3 + 1, 1, 0, "6")
        K2_ITER(kb3 + 2, 2, 1, "6")
    }
    K2_ITER(15, 0, 0, "0")
#undef K2_ITER
#undef STAGE

#pragma unroll
    for (int nt = 0; nt < 4; nt++) {
        int col = wn * 64 + nt * 16 + lane15;
        float bv = bias[col];
        int rbase = row0 + wm * 16 + kg * 4;
#pragma unroll
        for (int j = 0; j < 4; j++)
            out[(size_t)(rbase + j) * EMB + col] = acc[nt][j] + bv;
    }
}

// ============ K3: idx + lpos + l_neg (MFMA, B direct from L2) + CE partials ============
// 512 blocks x 512 threads (8 waves, 16 waves/CU): waves wgrp=0 handle N-chunks 0-7,
// wgrp=1 handle 8-15 — per-wave work halved, TLP doubled vs round 2 (which measured
// MfmaUtil 1.5% / occupancy 12.6% — pure latency-bound). Depth-2 register prefetch
// (named b0/b1, static indexing) forces ~8 B-loads in flight per wave. Per-block
// (sum_ce, valid) partials to private slots — NO same-address atomics, no
// threadfence, no counter; a 1-block finalize kernel reduces the 512 slots.
__global__ __launch_bounds__(512, 4) void ce_mfma_k(const float* __restrict__ q,
                                                    const float* __restrict__ k,
                                                    const ushort_t* __restrict__ Qt,
                                                    const int* __restrict__ rank,
                                                    const int* __restrict__ table,
                                                    const int* __restrict__ w,
                                                    const int* __restrict__ hist,
                                                    float* __restrict__ part) {
    __shared__ int   idx_lds[16];
    __shared__ float lpos_lds[16];
    __shared__ float mg[8][16][2];
    int t = threadIdx.x;
    int r0 = blockIdx.x * 16;

    // inline idx: idx[i] = table[w[i]][rank[i] % cnt]
    if (t < 16) {
        int i = r0 + t;
        int c = w[i];
        int cc = hist[c];
        idx_lds[t] = (cc > 0) ? table[c * 8192 + (rank[i] % cc)] : 0;
    }
    __syncthreads();

    // fused l_pos (fp32 exact): rows r0..r0+15, 16 threads x 8 floats each
    if (t < 256) {
        int rr = t >> 4;
        int o = (t & 15) * 8;
        const float4* qa = (const float4*)(q + (size_t)(r0 + rr) * EMB + o);
        const float4* ka = (const float4*)(k + (size_t)idx_lds[rr] * EMB + o);
        float4 a0 = qa[0], b0 = ka[0], a1 = qa[1], b1 = ka[1];
        float s = a0.x * b0.x + a0.y * b0.y + a0.z * b0.z + a0.w * b0.w
                + a1.x * b1.x + a1.y * b1.y + a1.z * b1.z + a1.w * b1.w;
        s += __shfl_xor(s, 1); s += __shfl_xor(s, 2);
        s += __shfl_xor(s, 4); s += __shfl_xor(s, 8);
        if ((t & 15) == 0) lpos_lds[rr] = s;
    }

    int wv = t >> 6, ln = t & 63;
    int wgrp = wv >> 2, wq = wv & 3;
    int lane15 = ln & 15, kg = ln >> 4;

    // A-frags direct from q global (all waves same 16 rows)
    short8 afr[4];
#pragma unroll
    for (int ks = 0; ks < 4; ks++) {
        const float4* p = (const float4*)(q + (size_t)(r0 + lane15) * EMB + ks * 32 + kg * 8);
        float4 a = p[0], b = p[1];
        uint4 pk;
        pk.x = pack2(a.x, a.y); pk.y = pack2(a.z, a.w);
        pk.z = pack2(b.x, b.y); pk.w = pack2(b.z, b.w);
        afr[ks] = __builtin_bit_cast(short8, pk);
    }

    f32x4 acc[8];
#pragma unroll
    for (int nc = 0; nc < 8; nc++) acc[nc] = (f32x4){0.f, 0.f, 0.f, 0.f};

    // B direct from L2-resident Qt; chunk c_i = wgrp*8 + nc, col = c_i*64 + wq*16 + lane15
    // (col & 15 == lane15, so swizzled granule index = col*16 + ((ks*4+kg) ^ lane15))
#define LOADB(DST, NCI)                                                          \
    { int n_g = ((wgrp * 8 + (NCI)) * 64) + wq * 16 + lane15;                    \
      const ushort_t* bp = Qt + (size_t)n_g * 128;                               \
      _Pragma("unroll")                                                          \
      for (int ks = 0; ks < 4; ks++)                                             \
          DST[ks] = *(const uint4*)(bp + (size_t)(((ks * 4 + kg) ^ lane15)) * 8); }

#define DO_MFMA(NC, B)                                                           \
    { _Pragma("unroll")                                                          \
      for (int ks = 0; ks < 4; ks++)                                             \
          acc[NC] = __builtin_amdgcn_mfma_f32_16x16x32_bf16(                     \
              afr[ks], __builtin_bit_cast(short8, (B)[ks]), acc[NC], 0, 0, 0); }

    uint4 b0[4], b1[4];
    LOADB(b0, 0)
    LOADB(b1, 1)  DO_MFMA(0, b0)
    LOADB(b0, 2)  DO_MFMA(1, b1)
    LOADB(b1, 3)  DO_MFMA(2, b0)
    LOADB(b0, 4)  DO_MFMA(3, b1)
    LOADB(b1, 5)  DO_MFMA(4, b0)
    LOADB(b0, 6)  DO_MFMA(5, b1)
    LOADB(b1, 7)  DO_MFMA(6, b0)
                  DO_MFMA(7, b1)
#undef LOADB
#undef DO_MFMA

    // per-wave softmax partials over its 8 chunks (32 logits/lane-row)
#pragma unroll
    for (int j = 0; j < 4; j++) {
        float mx = -1e30f;
#pragma unroll
        for (int nc = 0; nc < 8; nc++) mx = fmaxf(mx, acc[nc][j]);
        mx = fmaxf(mx, __shfl_xor(mx, 1));
        mx = fmaxf(mx, __shfl_xor(mx, 2));
        mx = fmaxf(mx, __shfl_xor(mx, 4));
        mx = fmaxf(mx, __shfl_xor(mx, 8));
        float s = 0.f;
#pragma unroll
        for (int nc = 0; nc < 8; nc++) s += __expf(acc[nc][j] - mx);
        s += __shfl_xor(s, 1);
        s += __shfl_xor(s, 2);
        s += __shfl_xor(s, 4);
        s += __shfl_xor(s, 8);
        if (lane15 == 0) {
            mg[wv][kg * 4 + j][0] = mx;
            mg[wv][kg * 4 + j][1] = s;
        }
    }
    __syncthreads();
    if (t < 16) {
        int i = r0 + t;
        float lp = lpos_lds[t];
        float m = lp;
#pragma unroll
        for (int v = 0; v < 8; v++) m = fmaxf(m, mg[v][t][0]);
        float l = __expf(lp - m);
#pragma unroll
        for (int v = 0; v < 8; v++) l += mg[v][t][1] * __expf(mg[v][t][0] - m);
        float ce = -(lp - m - __logf(l));
        float cv = 0.f, cc = 0.f;
        if (hist[w[i]] > 0) { cv = ce; cc = 1.f; }
        cv += __shfl_xor(cv, 1);  cc += __shfl_xor(cc, 1);
        cv += __shfl_xor(cv, 2);  cc += __shfl_xor(cc, 2);
        cv += __shfl_xor(cv, 4);  cc += __shfl_xor(cc, 4);
        cv += __shfl_xor(cv, 8);  cc += __shfl_xor(cc, 8);
        if (t == 0) {
            float2* pp = (float2*)part;
            pp[blockIdx.x] = make_float2(cv, cc);
        }
    }
}

// ============ K4: finalize — reduce 512 per-block partials, no atomics ============
__global__ __launch_bounds__(256) void fin_k(const float* __restrict__ part,
                                             float* __restrict__ outp) {
    int t = threadIdx.x;
    const float2* pp = (const float2*)part;
    float cv = 0.f, cc = 0.f;
    for (int i = t; i < 512; i += 256) {
        float2 p = pp[i];
        cv += p.x; cc += p.y;
    }
    cv += __shfl_xor(cv, 1);   cc += __shfl_xor(cc, 1);
    cv += __shfl_xor(cv, 2);   cc += __shfl_xor(cc, 2);
    cv += __shfl_xor(cv, 4);   cc += __shfl_xor(cc, 4);
    cv += __shfl_xor(cv, 8);   cc += __shfl_xor(cc, 8);
    cv += __shfl_xor(cv, 16);  cc += __shfl_xor(cc, 16);
    cv += __shfl_xor(cv, 32);  cc += __shfl_xor(cc, 32);
    __shared__ float sv[4], sc[4];
    if ((t & 63) == 0) { sv[t >> 6] = cv; sc[t >> 6] = cc; }
    __syncthreads();
    if (t == 0) {
        float s = sv[0] + sv[1] + sv[2] + sv[3];
        float c = sc[0] + sc[1] + sc[2] + sc[3];
        outp[0] = s / fmaxf(c, 1.0f);
    }
}

extern "C" void kernel_launch(void* const* d_in, const int* in_sizes, int n_in,
                              void* d_out, int out_size, void* d_ws, size_t ws_size,
                              hipStream_t stream) {
    const float* feats_strong = (const float*)d_in[0];
    const float* feats_weak   = (const float*)d_in[1];
    const int*   s_lab        = (const int*)d_in[2];
    const int*   w_lab        = (const int*)d_in[3];
    const float* Wq           = (const float*)d_in[4];
    const float* bq           = (const float*)d_in[5];
    const float* Wk           = (const float*)d_in[6];
    const float* bk           = (const float*)d_in[7];
    const float* queue        = (const float*)d_in[8];

    float*    wsf = (float*)d_ws;
    int*      wsi = (int*)d_ws;

    float*    q_g   = wsf + OFF_Q;
    float*    k_g   = wsf + OFF_K;
    int*      table = wsi + OFF_TABLE;
    ushort_t* Wtq   = (ushort_t*)(wsi + OFF_WTQ);
    ushort_t* Wtk   = (ushort_t*)(wsi + OFF_WTK);
    int*      hist  = wsi + OFF_HIST;
    int*      rank  = wsi + OFF_RANK;
    int*      cnt   = wsi + OFF_CNT;
    int*      bhs   = wsi + OFF_BHS;
    int*      bhw   = wsi + OFF_BHW;
    float*    accum = wsf + OFF_ACC;
    float*    part  = wsf + OFF_PART;
    ushort_t* Qt    = (ushort_t*)(wsi + OFF_QT);

    // K1: bf16 convert/transpose (BK=64 W-tiling, swizzled Qt) + histograms + init
    cvtbh_k<<<448, 256, 0, stream>>>(Wq, Wk, queue, s_lab, w_lab,
                                     Wtq, Wtk, Qt, bhs, bhw, accum, cnt);
    // K2: both encoder GEMMs (32x128 tiles, 3-buf counted-vmcnt pipeline) + ranktab
    enc_mfma_k<<<576, 256, 0, stream>>>(feats_weak, feats_strong, Wtq, Wtk, bq, bk, q_g, k_g,
                                        s_lab, w_lab, bhs, bhw, table, rank, hist);
    // K3: idx + lpos + l_neg GEMM (8 waves/block, depth-2 reg prefetch) + CE partials
    ce_mfma_k<<<512, 512, 0, stream>>>(q_g, k_g, Qt, rank, table, w_lab, hist, part);
    // K4: reduce partials -> loss
    fin_k<<<1, 256, 0, stream>>>(part, (float*)d_out);
}